// Round 1
// baseline (1475.504 us; speedup 1.0000x reference)
//
#include <hip/hip_runtime.h>
#include <stdint.h>

// Problem constants (B=4,S=2048,D=2048,E=8,H=2816,CAP_F=1.0)
#define T_TOK 8192
#define DDIM  2048
#define HDIM  2816
#define ENUM  8
#define CAPS  1024

typedef __attribute__((ext_vector_type(8))) __bf16 bf16x8;
typedef __attribute__((ext_vector_type(4))) float  floatx4;
typedef __attribute__((ext_vector_type(8))) unsigned short ushort8;

__device__ __forceinline__ unsigned short f2bf(float f) {
  union { float f; uint32_t u; } v; v.f = f;
  uint32_t r = v.u + 0x7fffu + ((v.u >> 16) & 1u);   // RNE
  return (unsigned short)(r >> 16);
}

// async global->LDS, 16B per lane. LDS dest must be wave-uniform base + lane*16.
__device__ __forceinline__ void async_copy16(const void* g, void* l) {
  __builtin_amdgcn_global_load_lds(
      (const __attribute__((address_space(1))) void*)(uintptr_t)g,
      (__attribute__((address_space(3))) void*)(uint32_t)(uintptr_t)l,
      16, 0, 0);
}

// ------ router fused with x fp32->bf16 cast: one read of x instead of two ---
// one wave per token: float4 loads, 8 iters over D=2048; writes xbf as ushort4.
__global__ __launch_bounds__(256) void router_cast_kernel(
    const float* __restrict__ x, const float* __restrict__ Wg,
    int* __restrict__ eidx, float* __restrict__ gate,
    unsigned short* __restrict__ xbf) {
  const int lane = threadIdx.x & 63;
  const int w    = threadIdx.x >> 6;
  const int t    = blockIdx.x * 4 + w;
  const float* xr = x + (size_t)t * DDIM;
  unsigned short* xo = xbf + (size_t)t * DDIM;
  float acc[ENUM];
#pragma unroll
  for (int e = 0; e < ENUM; ++e) acc[e] = 0.f;
#pragma unroll
  for (int k = 0; k < DDIM / 256; ++k) {          // 8 iterations
    const int d0 = (k * 64 + lane) * 4;
    float4 v = *(const float4*)&xr[d0];
    ushort4 r4;
    r4.x = f2bf(v.x); r4.y = f2bf(v.y); r4.z = f2bf(v.z); r4.w = f2bf(v.w);
    *(ushort4*)&xo[d0] = r4;
    const float xv[4] = {v.x, v.y, v.z, v.w};
#pragma unroll
    for (int j = 0; j < 4; ++j) {
      const float4* wr = (const float4*)&Wg[(size_t)(d0 + j) * ENUM];
      float4 w0 = wr[0], w1 = wr[1];
      acc[0] += xv[j] * w0.x; acc[1] += xv[j] * w0.y;
      acc[2] += xv[j] * w0.z; acc[3] += xv[j] * w0.w;
      acc[4] += xv[j] * w1.x; acc[5] += xv[j] * w1.y;
      acc[6] += xv[j] * w1.z; acc[7] += xv[j] * w1.w;
    }
  }
#pragma unroll
  for (int off = 32; off > 0; off >>= 1)
#pragma unroll
    for (int e = 0; e < ENUM; ++e) acc[e] += __shfl_xor(acc[e], off);
  if (lane == 0) {
    float m = acc[0]; int am = 0;
#pragma unroll
    for (int e = 1; e < ENUM; ++e) if (acc[e] > m) { m = acc[e]; am = e; }  // first-max wins
    float s = 0.f;
#pragma unroll
    for (int e = 0; e < ENUM; ++e) s += expf(acc[e] - m);
    eidx[t] = am;
    gate[t] = 1.0f / s;   // prob of argmax expert
  }
}

// --------- ordered scan: per-expert positions, capacity, slot maps ----------
__global__ __launch_bounds__(256) void scan_kernel(
    const int* __restrict__ eidx, const float* __restrict__ gate,
    int* __restrict__ slot2tok, float* __restrict__ gatek) {
  __shared__ int eid_s[T_TOK];
  __shared__ int wcnt[4][ENUM];
  __shared__ int base[ENUM];
  const int tid = threadIdx.x, lane = tid & 63, w = tid >> 6;
  for (int i = tid; i < T_TOK; i += 256) { eid_s[i] = eidx[i]; slot2tok[i] = -1; }
  if (tid < ENUM) base[tid] = 0;
  __syncthreads();
  const unsigned long long below = (1ull << lane) - 1ull;
  for (int chunk = 0; chunk < T_TOK / 256; ++chunk) {
    const int t = chunk * 256 + tid;
    const int e = eid_s[t];
    int rank_w = 0;
#pragma unroll
    for (int e0 = 0; e0 < ENUM; ++e0) {
      unsigned long long m = __ballot(e == e0);
      if (e0 == e) rank_w = __popcll(m & below);
      if (lane == e0) wcnt[w][e0] = __popcll(m);
    }
    __syncthreads();
    int pos = base[e] + rank_w;
    for (int w2 = 0; w2 < w; ++w2) pos += wcnt[w2][e];
    const bool keep = pos < CAPS;
    if (keep) slot2tok[e * CAPS + pos] = t;
    gatek[t] = keep ? gate[t] : 0.f;
    __syncthreads();
    if (tid < ENUM) base[tid] += wcnt[0][tid] + wcnt[1][tid] + wcnt[2][tid] + wcnt[3][tid];
    __syncthreads();
  }
}

// ---------------- fp32 [R,C] -> bf16 [C,R] transpose-cast -------------------
// float4 global reads, ushort2 global writes (was scalar/2B).
__global__ __launch_bounds__(256) void transpose_cast_kernel(
    const float* __restrict__ in, unsigned short* __restrict__ out, int R, int C) {
  __shared__ float tile[64][65];
  const int mat = blockIdx.z;
  in  += (size_t)mat * R * C;
  out += (size_t)mat * R * C;
  const int r0 = blockIdx.y * 64, c0 = blockIdx.x * 64;
  const int cc4 = (threadIdx.x & 15) * 4;
  const int rr  = threadIdx.x >> 4;       // 0..15
#pragma unroll
  for (int j = 0; j < 4; ++j) {
    int r = j * 16 + rr;
    float4 v = *(const float4*)&in[(size_t)(r0 + r) * C + c0 + cc4];
    tile[r][cc4 + 0] = v.x; tile[r][cc4 + 1] = v.y;
    tile[r][cc4 + 2] = v.z; tile[r][cc4 + 3] = v.w;
  }
  __syncthreads();
  const int cq  = threadIdx.x >> 5;       // 0..7
  const int tcc = (threadIdx.x & 31) * 2; // 0..62 even
#pragma unroll
  for (int j = 0; j < 8; ++j) {
    int c = j * 8 + cq;
    ushort2 r2;
    r2.x = f2bf(tile[tcc][c]);
    r2.y = f2bf(tile[tcc + 1][c]);
    *(ushort2*)&out[(size_t)(c0 + c) * R + r0 + tcc] = r2;
  }
}

// ------- GEMM1 fused dual-B: h = silu(A@W1^T)*(A@W3^T), tile 128x64(x2) -----
// A: bf16 [T,DDIM] (optionally row-gathered via slot2tok). B1,B3: bf16 [N=HDIM,K=DDIM] per expert.
template <bool GATHER>
__global__ __launch_bounds__(256, 2) void gemm13_kernel(
    const unsigned short* __restrict__ A, const int* __restrict__ s2t,
    const unsigned short* __restrict__ B1, const unsigned short* __restrict__ B3,
    unsigned short* __restrict__ Hout, int MperZ) {
  __shared__ unsigned short As [128 * 64];
  __shared__ unsigned short B1s[64 * 64];
  __shared__ unsigned short B3s[64 * 64];

  const int tid = threadIdx.x, lane = tid & 63, w = tid >> 6;
  const int wm = w >> 1, wn = w & 1;
  const int e  = blockIdx.z;
  const int n0 = blockIdx.x * 64;
  const int m0 = e * MperZ + blockIdx.y * 128;

  const size_t eoff = (size_t)e * HDIM * DDIM;
  const unsigned short* B1e = B1 + eoff;
  const unsigned short* B3e = B3 + eoff;

  const int rl = tid >> 3;          // 0..31 (staging row within chunk)
  const int kc = (tid & 7) * 8;     // staging k-offset (elems)

  const unsigned short* aptr[4];
#pragma unroll
  for (int c = 0; c < 4; ++c) {
    int row = m0 + c * 32 + rl;
    int ar;
    if (GATHER) { int t = s2t[row]; ar = (t < 0) ? 0 : t; }  // empty slot -> token 0, discarded later
    else ar = row;
    aptr[c] = A + (size_t)ar * DDIM + kc;
  }
  const unsigned short* bptr1[2];
  const unsigned short* bptr3[2];
#pragma unroll
  for (int c = 0; c < 2; ++c) {
    int row = n0 + c * 32 + rl;
    bptr1[c] = B1e + (size_t)row * DDIM + kc;
    bptr3[c] = B3e + (size_t)row * DDIM + kc;
  }
  unsigned short* lA  = &As [rl * 64 + kc];
  unsigned short* lB1 = &B1s[rl * 64 + kc];
  unsigned short* lB3 = &B3s[rl * 64 + kc];

  floatx4 acc1[4][2], acc3[4][2];
#pragma unroll
  for (int mf = 0; mf < 4; ++mf)
#pragma unroll
    for (int nf = 0; nf < 2; ++nf) {
      acc1[mf][nf] = (floatx4){0.f, 0.f, 0.f, 0.f};
      acc3[mf][nf] = (floatx4){0.f, 0.f, 0.f, 0.f};
    }
  const int quad = lane >> 4, l16 = lane & 15;

  for (int k0 = 0; k0 < DDIM; k0 += 64) {
    __syncthreads();
#pragma unroll
    for (int c = 0; c < 4; ++c) async_copy16(aptr[c] + k0, lA + c * 2048);
#pragma unroll
    for (int c = 0; c < 2; ++c) {
      async_copy16(bptr1[c] + k0, lB1 + c * 2048);
      async_copy16(bptr3[c] + k0, lB3 + c * 2048);
    }
    __syncthreads();
#pragma unroll
    for (int kk = 0; kk < 64; kk += 32) {
      bf16x8 af[4], b1f[2], b3f[2];
#pragma unroll
      for (int mf = 0; mf < 4; ++mf)
        af[mf] = *(const bf16x8*)&As[(wm * 64 + mf * 16 + l16) * 64 + kk + quad * 8];
#pragma unroll
      for (int nf = 0; nf < 2; ++nf) {
        b1f[nf] = *(const bf16x8*)&B1s[(wn * 32 + nf * 16 + l16) * 64 + kk + quad * 8];
        b3f[nf] = *(const bf16x8*)&B3s[(wn * 32 + nf * 16 + l16) * 64 + kk + quad * 8];
      }
#pragma unroll
      for (int mf = 0; mf < 4; ++mf)
#pragma unroll
        for (int nf = 0; nf < 2; ++nf) {
          acc1[mf][nf] = __builtin_amdgcn_mfma_f32_16x16x32_bf16(af[mf], b1f[nf], acc1[mf][nf], 0, 0, 0);
          acc3[mf][nf] = __builtin_amdgcn_mfma_f32_16x16x32_bf16(af[mf], b3f[nf], acc3[mf][nf], 0, 0, 0);
        }
    }
  }
  // epilogue: SwiGLU -> bf16 h. C/D layout: col=lane&15, row=quad*4+reg (m89/m91-verified)
#pragma unroll
  for (int mf = 0; mf < 4; ++mf)
#pragma unroll
    for (int nf = 0; nf < 2; ++nf)
#pragma unroll
      for (int r = 0; r < 4; ++r) {
        int m = m0 + wm * 64 + mf * 16 + quad * 4 + r;
        int n = n0 + wn * 32 + nf * 16 + l16;
        float v1 = acc1[mf][nf][r], v3 = acc3[mf][nf][r];
        float hv = (v1 / (1.f + __expf(-v1))) * v3;
        Hout[(size_t)m * HDIM + n] = f2bf(hv);
      }
}

// ------- GEMM2: oe = h @ W2^T, tile 128x128.
//   EPI 1 (shared, runs FIRST): out = oe   (covers all T_TOK rows; no memset needed)
//   EPI 0 (expert, runs SECOND): out[tok] += gate*oe  (scatter-add over kept slots)
template <int EPI>
__global__ __launch_bounds__(256, 2) void gemm2_kernel(
    const unsigned short* __restrict__ Hb, const unsigned short* __restrict__ B2,
    const int* __restrict__ s2t, const float* __restrict__ gk,
    float* __restrict__ Out, int MperZ) {
  __shared__ unsigned short As[128 * 64];
  __shared__ unsigned short Bs[128 * 64];
  __shared__ int toks[128];

  const int tid = threadIdx.x, lane = tid & 63, w = tid >> 6;
  const int wm = w >> 1, wn = w & 1;
  const int e  = blockIdx.z;
  const int n0 = blockIdx.x * 128;
  const int m0 = e * MperZ + blockIdx.y * 128;

  const unsigned short* B2e = B2 + (size_t)e * DDIM * HDIM;
  if (EPI == 0) { if (tid < 128) toks[tid] = s2t[m0 + tid]; }

  const int rl = tid >> 3;
  const int kc = (tid & 7) * 8;

  const unsigned short* aptr[4];
  const unsigned short* bptr[4];
#pragma unroll
  for (int c = 0; c < 4; ++c) {
    aptr[c] = Hb  + (size_t)(m0 + c * 32 + rl) * HDIM + kc;
    bptr[c] = B2e + (size_t)(n0 + c * 32 + rl) * HDIM + kc;
  }
  unsigned short* lA = &As[rl * 64 + kc];
  unsigned short* lB = &Bs[rl * 64 + kc];

  floatx4 acc[4][4];
#pragma unroll
  for (int mf = 0; mf < 4; ++mf)
#pragma unroll
    for (int nf = 0; nf < 4; ++nf) acc[mf][nf] = (floatx4){0.f, 0.f, 0.f, 0.f};
  const int quad = lane >> 4, l16 = lane & 15;

  for (int k0 = 0; k0 < HDIM; k0 += 64) {
    __syncthreads();
#pragma unroll
    for (int c = 0; c < 4; ++c) {
      async_copy16(aptr[c] + k0, lA + c * 2048);
      async_copy16(bptr[c] + k0, lB + c * 2048);
    }
    __syncthreads();
#pragma unroll
    for (int kk = 0; kk < 64; kk += 32) {
      bf16x8 af[4], bf[4];
#pragma unroll
      for (int mf = 0; mf < 4; ++mf)
        af[mf] = *(const bf16x8*)&As[(wm * 64 + mf * 16 + l16) * 64 + kk + quad * 8];
#pragma unroll
      for (int nf = 0; nf < 4; ++nf)
        bf[nf] = *(const bf16x8*)&Bs[(wn * 64 + nf * 16 + l16) * 64 + kk + quad * 8];
#pragma unroll
      for (int mf = 0; mf < 4; ++mf)
#pragma unroll
        for (int nf = 0; nf < 4; ++nf)
          acc[mf][nf] = __builtin_amdgcn_mfma_f32_16x16x32_bf16(af[mf], bf[nf], acc[mf][nf], 0, 0, 0);
    }
  }
#pragma unroll
  for (int mf = 0; mf < 4; ++mf)
#pragma unroll
    for (int nf = 0; nf < 4; ++nf)
#pragma unroll
      for (int r = 0; r < 4; ++r) {
        int ml = wm * 64 + mf * 16 + quad * 4 + r;
        int n  = n0 + wn * 64 + nf * 16 + l16;
        float v = acc[mf][nf][r];
        if (EPI == 0) {
          int t = toks[ml];
          if (t >= 0) {
            size_t o = (size_t)t * DDIM + n;
            Out[o] += gk[t] * v;      // shared-expert value already present
          }
        } else {
          size_t o = (size_t)(m0 + ml) * DDIM + n;
          Out[o] = v;                 // plain write: replaces memset + add
        }
      }
}

// ---------------------------------------------------------------------------
extern "C" void kernel_launch(void* const* d_in, const int* in_sizes, int n_in,
                              void* d_out, int out_size, void* d_ws, size_t ws_size,
                              hipStream_t stream) {
  const float* x   = (const float*)d_in[0];
  const float* Wg  = (const float*)d_in[1];
  const float* W1  = (const float*)d_in[2];
  const float* W3  = (const float*)d_in[3];
  const float* W2  = (const float*)d_in[4];
  const float* sw1 = (const float*)d_in[5];
  const float* sw3 = (const float*)d_in[6];
  const float* sw2 = (const float*)d_in[7];
  float* out = (float*)d_out;

  char* ws = (char*)d_ws;
  size_t off = 0;
  auto alloc = [&](size_t bytes) -> void* {
    void* p = ws + off;
    off = (off + bytes + 255) & ~(size_t)255;
    return p;
  };
  int*   eidx     = (int*)alloc((size_t)T_TOK * 4);
  float* gate     = (float*)alloc((size_t)T_TOK * 4);
  int*   slot2tok = (int*)alloc((size_t)T_TOK * 4);
  float* gatek    = (float*)alloc((size_t)T_TOK * 4);
  unsigned short* xbf  = (unsigned short*)alloc((size_t)T_TOK * DDIM * 2);
  unsigned short* W1t  = (unsigned short*)alloc((size_t)ENUM * HDIM * DDIM * 2);
  unsigned short* W3t  = (unsigned short*)alloc((size_t)ENUM * HDIM * DDIM * 2);
  unsigned short* W2t  = (unsigned short*)alloc((size_t)ENUM * DDIM * HDIM * 2);
  unsigned short* s1t  = (unsigned short*)alloc((size_t)HDIM * DDIM * 2);
  unsigned short* s3t  = (unsigned short*)alloc((size_t)HDIM * DDIM * 2);
  unsigned short* s2t  = (unsigned short*)alloc((size_t)DDIM * HDIM * 2);
  unsigned short* hexp = (unsigned short*)alloc((size_t)T_TOK * HDIM * 2);
  unsigned short* hsh  = (unsigned short*)alloc((size_t)T_TOK * HDIM * 2);
  if (off > ws_size) {  // workspace too small: emit zeros so the failure is identifiable
    hipMemsetAsync(d_out, 0, (size_t)out_size * 4, stream);
    return;
  }

  // router + x cast fused (x read once)
  router_cast_kernel<<<T_TOK / 4, 256, 0, stream>>>(x, Wg, eidx, gate, xbf);
  scan_kernel<<<1, 256, 0, stream>>>(eidx, gate, slot2tok, gatek);

  // weight transforms (fp32 [K,N] -> bf16 [N,K])
  transpose_cast_kernel<<<dim3(HDIM / 64, DDIM / 64, ENUM), 256, 0, stream>>>(W1, W1t, DDIM, HDIM);
  transpose_cast_kernel<<<dim3(HDIM / 64, DDIM / 64, ENUM), 256, 0, stream>>>(W3, W3t, DDIM, HDIM);
  transpose_cast_kernel<<<dim3(DDIM / 64, HDIM / 64, ENUM), 256, 0, stream>>>(W2, W2t, HDIM, DDIM);
  transpose_cast_kernel<<<dim3(HDIM / 64, DDIM / 64, 1), 256, 0, stream>>>(sw1, s1t, DDIM, HDIM);
  transpose_cast_kernel<<<dim3(HDIM / 64, DDIM / 64, 1), 256, 0, stream>>>(sw3, s3t, DDIM, HDIM);
  transpose_cast_kernel<<<dim3(DDIM / 64, HDIM / 64, 1), 256, 0, stream>>>(sw2, s2t, HDIM, DDIM);

  // hidden activations
  gemm13_kernel<true><<<dim3(HDIM / 64, CAPS / 128, ENUM), 256, 0, stream>>>(
      xbf, slot2tok, W1t, W3t, hexp, CAPS);
  gemm13_kernel<false><<<dim3(HDIM / 64, T_TOK / 128, 1), 256, 0, stream>>>(
      xbf, nullptr, s1t, s3t, hsh, T_TOK);

  // down-projections: shared writes out fully, expert scatter-adds on top
  gemm2_kernel<1><<<dim3(DDIM / 128, T_TOK / 128, 1), 256, 0, stream>>>(
      hsh, s2t, nullptr, nullptr, out, T_TOK);
  gemm2_kernel<0><<<dim3(DDIM / 128, CAPS / 128, ENUM), 256, 0, stream>>>(
      hexp, W2t, slot2tok, gatek, out, CAPS);
}

// Round 2
// 1375.452 us; speedup vs baseline: 1.0727x; 1.0727x over previous
//
#include <hip/hip_runtime.h>
#include <stdint.h>

// Problem constants (B=4,S=2048,D=2048,E=8,H=2816,CAP_F=1.0)
#define T_TOK 8192
#define DDIM  2048
#define HDIM  2816
#define ENUM  8
#define CAPS  1024
#define NP13  (2 * HDIM)   // 5632 interleaved W1/W3 rows per expert

typedef __attribute__((ext_vector_type(8))) __bf16 bf16x8;
typedef __attribute__((ext_vector_type(4))) float  floatx4;

__device__ __forceinline__ unsigned short f2bf(float f) {
  union { float f; uint32_t u; } v; v.f = f;
  uint32_t r = v.u + 0x7fffu + ((v.u >> 16) & 1u);   // RNE
  return (unsigned short)(r >> 16);
}

// async global->LDS, 16B per lane. LDS dest must be wave-uniform base + lane*16.
__device__ __forceinline__ void async_copy16(const void* g, void* l) {
  __builtin_amdgcn_global_load_lds(
      (const __attribute__((address_space(1))) void*)(uintptr_t)g,
      (__attribute__((address_space(3))) void*)(uint32_t)(uintptr_t)l,
      16, 0, 0);
}

// ------ router fused with x fp32->bf16 cast: one read of x ------------------
__global__ __launch_bounds__(256) void router_cast_kernel(
    const float* __restrict__ x, const float* __restrict__ Wg,
    int* __restrict__ eidx, float* __restrict__ gate,
    unsigned short* __restrict__ xbf) {
  const int lane = threadIdx.x & 63;
  const int w    = threadIdx.x >> 6;
  const int t    = blockIdx.x * 4 + w;
  const float* xr = x + (size_t)t * DDIM;
  unsigned short* xo = xbf + (size_t)t * DDIM;
  float acc[ENUM];
#pragma unroll
  for (int e = 0; e < ENUM; ++e) acc[e] = 0.f;
#pragma unroll
  for (int k = 0; k < DDIM / 256; ++k) {
    const int d0 = (k * 64 + lane) * 4;
    float4 v = *(const float4*)&xr[d0];
    ushort4 r4;
    r4.x = f2bf(v.x); r4.y = f2bf(v.y); r4.z = f2bf(v.z); r4.w = f2bf(v.w);
    *(ushort4*)&xo[d0] = r4;
    const float xv[4] = {v.x, v.y, v.z, v.w};
#pragma unroll
    for (int j = 0; j < 4; ++j) {
      const float4* wr = (const float4*)&Wg[(size_t)(d0 + j) * ENUM];
      float4 w0 = wr[0], w1 = wr[1];
      acc[0] += xv[j] * w0.x; acc[1] += xv[j] * w0.y;
      acc[2] += xv[j] * w0.z; acc[3] += xv[j] * w0.w;
      acc[4] += xv[j] * w1.x; acc[5] += xv[j] * w1.y;
      acc[6] += xv[j] * w1.z; acc[7] += xv[j] * w1.w;
    }
  }
#pragma unroll
  for (int off = 32; off > 0; off >>= 1)
#pragma unroll
    for (int e = 0; e < ENUM; ++e) acc[e] += __shfl_xor(acc[e], off);
  if (lane == 0) {
    float m = acc[0]; int am = 0;
#pragma unroll
    for (int e = 1; e < ENUM; ++e) if (acc[e] > m) { m = acc[e]; am = e; }
    float s = 0.f;
#pragma unroll
    for (int e = 0; e < ENUM; ++e) s += expf(acc[e] - m);
    eidx[t] = am;
    gate[t] = 1.0f / s;
  }
}

// --------- ordered scan: per-expert positions, capacity, slot maps ----------
__global__ __launch_bounds__(256) void scan_kernel(
    const int* __restrict__ eidx, const float* __restrict__ gate,
    int* __restrict__ slot2tok, float* __restrict__ gatek) {
  __shared__ int eid_s[T_TOK];
  __shared__ int wcnt[4][ENUM];
  __shared__ int base[ENUM];
  const int tid = threadIdx.x, lane = tid & 63, w = tid >> 6;
  for (int i = tid; i < T_TOK; i += 256) { eid_s[i] = eidx[i]; slot2tok[i] = -1; }
  if (tid < ENUM) base[tid] = 0;
  __syncthreads();
  const unsigned long long below = (1ull << lane) - 1ull;
  for (int chunk = 0; chunk < T_TOK / 256; ++chunk) {
    const int t = chunk * 256 + tid;
    const int e = eid_s[t];
    int rank_w = 0;
#pragma unroll
    for (int e0 = 0; e0 < ENUM; ++e0) {
      unsigned long long m = __ballot(e == e0);
      if (e0 == e) rank_w = __popcll(m & below);
      if (lane == e0) wcnt[w][e0] = __popcll(m);
    }
    __syncthreads();
    int pos = base[e] + rank_w;
    for (int w2 = 0; w2 < w; ++w2) pos += wcnt[w2][e];
    const bool keep = pos < CAPS;
    if (keep) slot2tok[e * CAPS + pos] = t;
    gatek[t] = keep ? gate[t] : 0.f;
    __syncthreads();
    if (tid < ENUM) base[tid] += wcnt[0][tid] + wcnt[1][tid] + wcnt[2][tid] + wcnt[3][tid];
    __syncthreads();
  }
}

// ---------------- fp32 [R,C] -> bf16 [C,R] transpose-cast -------------------
// mode 0: out row = h.  mode 1/2: interleaved W13 row = (h>>4)*32 + (mode==2)*16 + (h&15).
__global__ __launch_bounds__(256) void transpose_cast_kernel(
    const float* __restrict__ in, unsigned short* __restrict__ out,
    int R, int C, int mode, size_t oslab) {
  __shared__ float tile[64][65];
  const int mat = blockIdx.z;
  in  += (size_t)mat * R * C;
  out += (size_t)mat * oslab;
  const int r0 = blockIdx.y * 64, c0 = blockIdx.x * 64;
  const int cc4 = (threadIdx.x & 15) * 4;
  const int rr  = threadIdx.x >> 4;
#pragma unroll
  for (int j = 0; j < 4; ++j) {
    int r = j * 16 + rr;
    float4 v = *(const float4*)&in[(size_t)(r0 + r) * C + c0 + cc4];
    tile[r][cc4 + 0] = v.x; tile[r][cc4 + 1] = v.y;
    tile[r][cc4 + 2] = v.z; tile[r][cc4 + 3] = v.w;
  }
  __syncthreads();
  const int cq  = threadIdx.x >> 5;
  const int tcc = (threadIdx.x & 31) * 2;
#pragma unroll
  for (int j = 0; j < 8; ++j) {
    int c = j * 8 + cq;
    int h = c0 + c;
    int rp = (mode == 0) ? h : (((h >> 4) << 5) + ((mode == 2) ? 16 : 0) + (h & 15));
    ushort2 r2;
    r2.x = f2bf(tile[tcc][c]);
    r2.y = f2bf(tile[tcc + 1][c]);
    *(ushort2*)&out[(size_t)rp * R + r0 + tcc] = r2;
  }
}

// ===================== 256x256 8-phase MFMA GEMM core =======================
// C[m0:256, n0:256] = A[m,K] * B[n,K]^T.  8 waves (2M x 4N), per-wave 128x64.
// LDS: 2 buffers x (A 256x64 + B 256x64) bf16 = 128 KiB, bank-swizzled.
// EPI 0: SwiGLU over interleaved W13 fragment pairs -> bf16 Hout.
// EPI 1: plain f32 write (shared-expert down-proj).
// EPI 2: gated scatter-add via slot2tok (expert down-proj).
template <int EPI, bool GATHER, int KDIM>
__global__ __launch_bounds__(512, 2) void gemm256(
    const unsigned short* __restrict__ A, const int* __restrict__ s2t,
    const unsigned short* __restrict__ Bw, size_t bslab,
    void* __restrict__ OutP, const float* __restrict__ gk, int MperZ) {
  __shared__ unsigned short lds[65536];   // 128 KiB: buf{0,1} x {A:16384, B:16384} ushorts
  __shared__ int toks[256];

  const int tid = threadIdx.x, lane = tid & 63, w = tid >> 6;
  const int l16 = lane & 15, quad = lane >> 4;
  const int wm = w >> 2, wn = w & 3;

  // T1 bijective XCD swizzle (all grids have nwg % 8 == 0)
  const int nbx = gridDim.x, nby = gridDim.y;
  const int bid = blockIdx.x + nbx * (blockIdx.y + nby * blockIdx.z);
  const int nwg = nbx * nby * (int)gridDim.z;
  int lg = (bid & 7) * (nwg >> 3) + (bid >> 3);
  const int bz = lg / (nbx * nby); lg -= bz * nbx * nby;
  const int by = lg / nbx, bx = lg - by * nbx;

  const int n0 = bx * 256;
  const int m0 = bz * MperZ + by * 256;
  const unsigned short* Be = Bw + (size_t)bz * bslab;

  if (EPI == 2) { if (tid < 256) toks[tid] = s2t[m0 + tid]; }

  // ---- staging addresses: wave w + load j cover one 1KiB chunk (8 rows) ----
  // swizzle: physical byte = logical byte ^ ((row&7)<<4)  (involution, bits 4-6)
  const int cst = ((lane & 7) ^ (lane >> 3)) * 8;      // logical k-offset (elems) for this lane
  const unsigned short* aptr[4];
  const unsigned short* bptr[4];
  int ldso[4];                                          // wave-uniform LDS chunk offsets (ushorts)
#pragma unroll
  for (int h = 0; h < 2; ++h)
#pragma unroll
    for (int j = 0; j < 2; ++j) {
      const int r = h * 128 + (j * 8 + w) * 8 + (lane >> 3);
      int arow = m0 + r;
      if (GATHER) { int t = s2t[arow]; arow = (t < 0) ? 0 : t; }
      aptr[h * 2 + j] = A + (size_t)arow * KDIM + cst;
      bptr[h * 2 + j] = Be + (size_t)(n0 + r) * KDIM + cst;
      ldso[h * 2 + j] = h * 8192 + (j * 8 + w) * 512;
    }

  floatx4 acc[8][4];
#pragma unroll
  for (int i = 0; i < 8; ++i)
#pragma unroll
    for (int j = 0; j < 4; ++j) acc[i][j] = (floatx4){0.f, 0.f, 0.f, 0.f};

  const int cswz = (quad * 16) ^ ((l16 & 7) << 4);     // phys byte col for kk=0

#define STAGE_A(bt, k0e) {                                              \
    async_copy16(aptr[0] + (k0e), &lds[(bt) * 32768 + ldso[0]]);        \
    async_copy16(aptr[1] + (k0e), &lds[(bt) * 32768 + ldso[1]]);        \
    async_copy16(aptr[2] + (k0e), &lds[(bt) * 32768 + ldso[2]]);        \
    async_copy16(aptr[3] + (k0e), &lds[(bt) * 32768 + ldso[3]]); }
#define STAGE_B(bt, k0e) {                                              \
    async_copy16(bptr[0] + (k0e), &lds[(bt) * 32768 + 16384 + ldso[0]]);\
    async_copy16(bptr[1] + (k0e), &lds[(bt) * 32768 + 16384 + ldso[1]]);\
    async_copy16(bptr[2] + (k0e), &lds[(bt) * 32768 + 16384 + ldso[2]]);\
    async_copy16(bptr[3] + (k0e), &lds[(bt) * 32768 + 16384 + ldso[3]]); }

#define LD_A(bt, R, kb) (*(const bf16x8*)((const char*)&lds[(bt) * 32768 + (R) * 64] + (cswz ^ (kb))))
#define LD_B(bt, R, kb) (*(const bf16x8*)((const char*)&lds[(bt) * 32768 + 16384 + (R) * 64] + (cswz ^ (kb))))

  // phase: {12 ds_read ; stage ; barrier ; setprio(1) 16 MFMA setprio(0) ; [vmcnt] barrier}
#define DO_PHASE(QM, QN, BT, STAGE_STMT, VMW) {                               \
    bf16x8 a0[4], a1[4], b0[2], b1[2];                                        \
    _Pragma("unroll") for (int mf = 0; mf < 4; ++mf) {                        \
      const int R = wm * 128 + (QM) * 64 + mf * 16 + l16;                     \
      a0[mf] = LD_A(BT, R, 0); a1[mf] = LD_A(BT, R, 64);                      \
    }                                                                         \
    _Pragma("unroll") for (int nf = 0; nf < 2; ++nf) {                        \
      const int R = wn * 64 + (QN) * 32 + nf * 16 + l16;                      \
      b0[nf] = LD_B(BT, R, 0); b1[nf] = LD_B(BT, R, 64);                      \
    }                                                                         \
    STAGE_STMT;                                                               \
    __builtin_amdgcn_s_barrier();                                             \
    __builtin_amdgcn_s_setprio(1);                                            \
    _Pragma("unroll") for (int mf = 0; mf < 4; ++mf)                          \
      _Pragma("unroll") for (int nf = 0; nf < 2; ++nf) {                      \
        acc[(QM)*4+mf][(QN)*2+nf] = __builtin_amdgcn_mfma_f32_16x16x32_bf16(  \
            a0[mf], b0[nf], acc[(QM)*4+mf][(QN)*2+nf], 0, 0, 0);              \
        acc[(QM)*4+mf][(QN)*2+nf] = __builtin_amdgcn_mfma_f32_16x16x32_bf16(  \
            a1[mf], b1[nf], acc[(QM)*4+mf][(QN)*2+nf], 0, 0, 0);              \
      }                                                                       \
    __builtin_amdgcn_s_setprio(0);                                            \
    if (VMW) { asm volatile("s_waitcnt vmcnt(0)" ::: "memory"); }             \
    __builtin_amdgcn_s_barrier();                                             \
  }

  // prologue: tile 0 -> buf0 (also makes toks visible)
  STAGE_A(0, 0); STAGE_B(0, 0);
  __syncthreads();

  const int NIT = KDIM / 128;   // 2 K-tiles (BK=64) per iteration
  for (int it = 0; it < NIT; ++it) {
    const int k0 = it * 128;
    const bool pf = (it + 1 < NIT);
    // phases 0-3: consume buf0 (tile 2it); stage tile 2it+1 -> buf1 at ph 0,1
    DO_PHASE(0, 0, 0, STAGE_A(1, k0 + 64), 0);
    DO_PHASE(0, 1, 0, STAGE_B(1, k0 + 64), 0);
    DO_PHASE(1, 0, 0, {;}, 0);
    DO_PHASE(1, 1, 0, {;}, 1);   // vmcnt(0): exactly tile 2it+1's 8 loads
    // phases 4-7: consume buf1 (tile 2it+1); stage tile 2it+2 -> buf0 at ph 4,5
    DO_PHASE(0, 0, 1, if (pf) STAGE_A(0, k0 + 128), 0);
    DO_PHASE(0, 1, 1, if (pf) STAGE_B(0, k0 + 128), 0);
    DO_PHASE(1, 0, 1, {;}, 0);
    DO_PHASE(1, 1, 1, {;}, 1);   // vmcnt(0): exactly tile 2it+2's 8 loads
  }
#undef DO_PHASE
#undef LD_A
#undef LD_B
#undef STAGE_A
#undef STAGE_B

  // ------------------------------- epilogue ---------------------------------
  if (EPI == 0) {
    // interleaved W13: within a quadrant, nf=0 frag = W1, nf=1 frag = W3 of the
    // SAME 16 hidden cols. h = n0/2 + wn*32 + qn*16 + l16.
    unsigned short* Hout = (unsigned short*)OutP;
#pragma unroll
    for (int qm = 0; qm < 2; ++qm)
#pragma unroll
      for (int mf = 0; mf < 4; ++mf) {
        const int mrow = m0 + wm * 128 + qm * 64 + mf * 16 + quad * 4;
#pragma unroll
        for (int qn = 0; qn < 2; ++qn) {
          const int hcol = (n0 >> 1) + wn * 32 + qn * 16 + l16;
#pragma unroll
          for (int rr = 0; rr < 4; ++rr) {
            float v1 = acc[qm * 4 + mf][qn * 2 + 0][rr];
            float v3 = acc[qm * 4 + mf][qn * 2 + 1][rr];
            float hv = (v1 / (1.f + __expf(-v1))) * v3;
            Hout[(size_t)(mrow + rr) * HDIM + hcol] = f2bf(hv);
          }
        }
      }
  } else {
    float* Out = (float*)OutP;
#pragma unroll
    for (int qm = 0; qm < 2; ++qm)
#pragma unroll
      for (int mf = 0; mf < 4; ++mf) {
        const int mb = wm * 128 + qm * 64 + mf * 16 + quad * 4;
#pragma unroll
        for (int qn = 0; qn < 2; ++qn)
#pragma unroll
          for (int nf = 0; nf < 2; ++nf) {
            const int n = n0 + wn * 64 + qn * 32 + nf * 16 + l16;
#pragma unroll
            for (int rr = 0; rr < 4; ++rr) {
              const float v = acc[qm * 4 + mf][qn * 2 + nf][rr];
              if (EPI == 1) {
                Out[(size_t)(m0 + mb + rr) * DDIM + n] = v;
              } else {
                const int t = toks[mb + rr];
                if (t >= 0) Out[(size_t)t * DDIM + n] += gk[t] * v;
              }
            }
          }
      }
  }
}

// ---------------------------------------------------------------------------
extern "C" void kernel_launch(void* const* d_in, const int* in_sizes, int n_in,
                              void* d_out, int out_size, void* d_ws, size_t ws_size,
                              hipStream_t stream) {
  const float* x   = (const float*)d_in[0];
  const float* Wg  = (const float*)d_in[1];
  const float* W1  = (const float*)d_in[2];
  const float* W3  = (const float*)d_in[3];
  const float* W2  = (const float*)d_in[4];
  const float* sw1 = (const float*)d_in[5];
  const float* sw3 = (const float*)d_in[6];
  const float* sw2 = (const float*)d_in[7];
  float* out = (float*)d_out;

  char* ws = (char*)d_ws;
  size_t off = 0;
  auto alloc = [&](size_t bytes) -> void* {
    void* p = ws + off;
    off = (off + bytes + 255) & ~(size_t)255;
    return p;
  };
  int*   eidx     = (int*)alloc((size_t)T_TOK * 4);
  float* gate     = (float*)alloc((size_t)T_TOK * 4);
  int*   slot2tok = (int*)alloc((size_t)T_TOK * 4);
  float* gatek    = (float*)alloc((size_t)T_TOK * 4);
  unsigned short* xbf  = (unsigned short*)alloc((size_t)T_TOK * DDIM * 2);
  unsigned short* W13t = (unsigned short*)alloc((size_t)ENUM * NP13 * DDIM * 2);
  unsigned short* W2t  = (unsigned short*)alloc((size_t)ENUM * DDIM * HDIM * 2);
  unsigned short* s13t = (unsigned short*)alloc((size_t)NP13 * DDIM * 2);
  unsigned short* ssw2 = (unsigned short*)alloc((size_t)DDIM * HDIM * 2);
  unsigned short* hexp = (unsigned short*)alloc((size_t)T_TOK * HDIM * 2);
  unsigned short* hsh  = (unsigned short*)alloc((size_t)T_TOK * HDIM * 2);
  if (off > ws_size) {
    hipMemsetAsync(d_out, 0, (size_t)out_size * 4, stream);
    return;
  }

  router_cast_kernel<<<T_TOK / 4, 256, 0, stream>>>(x, Wg, eidx, gate, xbf);
  scan_kernel<<<1, 256, 0, stream>>>(eidx, gate, slot2tok, gatek);

  // weight transforms: W1/W3 -> interleaved W13 (modes 1/2); W2 plain (mode 0)
  transpose_cast_kernel<<<dim3(HDIM / 64, DDIM / 64, ENUM), 256, 0, stream>>>(
      W1, W13t, DDIM, HDIM, 1, (size_t)NP13 * DDIM);
  transpose_cast_kernel<<<dim3(HDIM / 64, DDIM / 64, ENUM), 256, 0, stream>>>(
      W3, W13t, DDIM, HDIM, 2, (size_t)NP13 * DDIM);
  transpose_cast_kernel<<<dim3(DDIM / 64, HDIM / 64, ENUM), 256, 0, stream>>>(
      W2, W2t, HDIM, DDIM, 0, (size_t)DDIM * HDIM);
  transpose_cast_kernel<<<dim3(HDIM / 64, DDIM / 64, 1), 256, 0, stream>>>(
      sw1, s13t, DDIM, HDIM, 1, 0);
  transpose_cast_kernel<<<dim3(HDIM / 64, DDIM / 64, 1), 256, 0, stream>>>(
      sw3, s13t, DDIM, HDIM, 2, 0);
  transpose_cast_kernel<<<dim3(DDIM / 64, HDIM / 64, 1), 256, 0, stream>>>(
      sw2, ssw2, HDIM, DDIM, 0, 0);

  // hidden activations: h = silu(x@W1)*(x@W3)  (256^2 8-phase core, EPI=0)
  gemm256<0, true,  DDIM><<<dim3(NP13 / 256, CAPS / 256, ENUM), 512, 0, stream>>>(
      xbf, slot2tok, W13t, (size_t)NP13 * DDIM, hexp, nullptr, CAPS);
  gemm256<0, false, DDIM><<<dim3(NP13 / 256, T_TOK / 256, 1), 512, 0, stream>>>(
      xbf, nullptr, s13t, 0, hsh, nullptr, T_TOK);

  // down-projections: shared writes out fully (EPI=1), expert scatter-adds (EPI=2)
  gemm256<1, false, HDIM><<<dim3(DDIM / 256, T_TOK / 256, 1), 512, 0, stream>>>(
      hsh, nullptr, ssw2, 0, out, nullptr, T_TOK);
  gemm256<2, false, HDIM><<<dim3(DDIM / 256, CAPS / 256, ENUM), 512, 0, stream>>>(
      hexp, slot2tok, W2t, (size_t)DDIM * HDIM, out, gatek, CAPS);
}

// Round 3
// 1368.837 us; speedup vs baseline: 1.0779x; 1.0048x over previous
//
#include <hip/hip_runtime.h>
#include <stdint.h>

// Problem constants (B=4,S=2048,D=2048,E=8,H=2816,CAP_F=1.0)
#define T_TOK 8192
#define DDIM  2048
#define HDIM  2816
#define ENUM  8
#define CAPS  1024
#define NP13  (2 * HDIM)   // 5632 interleaved W1/W3 rows per expert

typedef __attribute__((ext_vector_type(8))) __bf16 bf16x8;
typedef __attribute__((ext_vector_type(4))) float  floatx4;

__device__ __forceinline__ unsigned short f2bf(float f) {
  union { float f; uint32_t u; } v; v.f = f;
  uint32_t r = v.u + 0x7fffu + ((v.u >> 16) & 1u);   // RNE
  return (unsigned short)(r >> 16);
}

// async global->LDS, 16B per lane. LDS dest = wave-uniform base + lane*16.
__device__ __forceinline__ void async_copy16(const void* g, void* l) {
  __builtin_amdgcn_global_load_lds(
      (const __attribute__((address_space(1))) void*)(uintptr_t)g,
      (__attribute__((address_space(3))) void*)(uint32_t)(uintptr_t)l,
      16, 0, 0);
}

// ------ router fused with x fp32->bf16 cast: one read of x ------------------
__global__ __launch_bounds__(256) void router_cast_kernel(
    const float* __restrict__ x, const float* __restrict__ Wg,
    int* __restrict__ eidx, float* __restrict__ gate,
    unsigned short* __restrict__ xbf) {
  const int lane = threadIdx.x & 63;
  const int w    = threadIdx.x >> 6;
  const int t    = blockIdx.x * 4 + w;
  const float* xr = x + (size_t)t * DDIM;
  unsigned short* xo = xbf + (size_t)t * DDIM;
  float acc[ENUM];
#pragma unroll
  for (int e = 0; e < ENUM; ++e) acc[e] = 0.f;
#pragma unroll
  for (int k = 0; k < DDIM / 256; ++k) {
    const int d0 = (k * 64 + lane) * 4;
    float4 v = *(const float4*)&xr[d0];
    ushort4 r4;
    r4.x = f2bf(v.x); r4.y = f2bf(v.y); r4.z = f2bf(v.z); r4.w = f2bf(v.w);
    *(ushort4*)&xo[d0] = r4;
    const float xv[4] = {v.x, v.y, v.z, v.w};
#pragma unroll
    for (int j = 0; j < 4; ++j) {
      const float4* wr = (const float4*)&Wg[(size_t)(d0 + j) * ENUM];
      float4 w0 = wr[0], w1 = wr[1];
      acc[0] += xv[j] * w0.x; acc[1] += xv[j] * w0.y;
      acc[2] += xv[j] * w0.z; acc[3] += xv[j] * w0.w;
      acc[4] += xv[j] * w1.x; acc[5] += xv[j] * w1.y;
      acc[6] += xv[j] * w1.z; acc[7] += xv[j] * w1.w;
    }
  }
#pragma unroll
  for (int off = 32; off > 0; off >>= 1)
#pragma unroll
    for (int e = 0; e < ENUM; ++e) acc[e] += __shfl_xor(acc[e], off);
  if (lane == 0) {
    float m = acc[0]; int am = 0;
#pragma unroll
    for (int e = 1; e < ENUM; ++e) if (acc[e] > m) { m = acc[e]; am = e; }
    float s = 0.f;
#pragma unroll
    for (int e = 0; e < ENUM; ++e) s += expf(acc[e] - m);
    eidx[t] = am;
    gate[t] = 1.0f / s;
  }
}

// --------- ordered scan: per-expert positions, capacity, slot maps ----------
__global__ __launch_bounds__(256) void scan_kernel(
    const int* __restrict__ eidx, const float* __restrict__ gate,
    int* __restrict__ slot2tok, float* __restrict__ gatek) {
  __shared__ int eid_s[T_TOK];
  __shared__ int wcnt[4][ENUM];
  __shared__ int base[ENUM];
  const int tid = threadIdx.x, lane = tid & 63, w = tid >> 6;
  for (int i = tid; i < T_TOK; i += 256) { eid_s[i] = eidx[i]; slot2tok[i] = -1; }
  if (tid < ENUM) base[tid] = 0;
  __syncthreads();
  const unsigned long long below = (1ull << lane) - 1ull;
  for (int chunk = 0; chunk < T_TOK / 256; ++chunk) {
    const int t = chunk * 256 + tid;
    const int e = eid_s[t];
    int rank_w = 0;
#pragma unroll
    for (int e0 = 0; e0 < ENUM; ++e0) {
      unsigned long long m = __ballot(e == e0);
      if (e0 == e) rank_w = __popcll(m & below);
      if (lane == e0) wcnt[w][e0] = __popcll(m);
    }
    __syncthreads();
    int pos = base[e] + rank_w;
    for (int w2 = 0; w2 < w; ++w2) pos += wcnt[w2][e];
    const bool keep = pos < CAPS;
    if (keep) slot2tok[e * CAPS + pos] = t;
    gatek[t] = keep ? gate[t] : 0.f;
    __syncthreads();
    if (tid < ENUM) base[tid] += wcnt[0][tid] + wcnt[1][tid] + wcnt[2][tid] + wcnt[3][tid];
    __syncthreads();
  }
}

// ---------------- fp32 [R,C] -> bf16 [C,R] transpose-cast -------------------
// mode 0: out row = h.  mode 1/2: interleaved W13 row = (h>>4)*32 + (mode==2)*16 + (h&15).
__global__ __launch_bounds__(256) void transpose_cast_kernel(
    const float* __restrict__ in, unsigned short* __restrict__ out,
    int R, int C, int mode, size_t oslab) {
  __shared__ float tile[64][65];
  const int mat = blockIdx.z;
  in  += (size_t)mat * R * C;
  out += (size_t)mat * oslab;
  const int r0 = blockIdx.y * 64, c0 = blockIdx.x * 64;
  const int cc4 = (threadIdx.x & 15) * 4;
  const int rr  = threadIdx.x >> 4;
#pragma unroll
  for (int j = 0; j < 4; ++j) {
    int r = j * 16 + rr;
    float4 v = *(const float4*)&in[(size_t)(r0 + r) * C + c0 + cc4];
    tile[r][cc4 + 0] = v.x; tile[r][cc4 + 1] = v.y;
    tile[r][cc4 + 2] = v.z; tile[r][cc4 + 3] = v.w;
  }
  __syncthreads();
  const int cq  = threadIdx.x >> 5;
  const int tcc = (threadIdx.x & 31) * 2;
#pragma unroll
  for (int j = 0; j < 8; ++j) {
    int c = j * 8 + cq;
    int h = c0 + c;
    int rp = (mode == 0) ? h : (((h >> 4) << 5) + ((mode == 2) ? 16 : 0) + (h & 15));
    ushort2 r2;
    r2.x = f2bf(tile[tcc][c]);
    r2.y = f2bf(tile[tcc + 1][c]);
    *(ushort2*)&out[(size_t)rp * R + r0 + tcc] = r2;
  }
}

// ============ 256x256 MFMA GEMM core, BK=32, 4-slot counted-vmcnt ===========
// C[m0:256, n0:256] = A[m,K] * B[n,K]^T.  8 waves (2M x 4N), per-wave 128x64.
// LDS: 4 slots x (A 256x32 + B 256x32) bf16 = 128 KiB. Stage depth 3 tiles,
// s_waitcnt vmcnt(8) per tile (T4 counted accounting: 2 newer tiles in flight).
// Swizzle: phys 16B-pos = quad ^ (row&3) (involution; inverse applied on the
// per-lane global SOURCE so global_load_lds stays linear — rule #21).
// EPI 0: SwiGLU over interleaved W13 fragment pairs -> bf16 Hout.
// EPI 1: plain f32 write (shared-expert down-proj).
// EPI 2: gated scatter-add via slot2tok (expert down-proj).
template <int EPI, bool GATHER, int KDIM>
__global__ __launch_bounds__(512, 2) void gemm256(
    const unsigned short* __restrict__ A, const int* __restrict__ s2t,
    const unsigned short* __restrict__ Bw, size_t bslab,
    void* __restrict__ OutP, const float* __restrict__ gk, int MperZ) {
  __shared__ unsigned short lds[65536];   // 4 slots x 16384 ushorts (A:8192, B:8192)
  __shared__ int toks[256];

  const int tid = threadIdx.x, lane = tid & 63, w = tid >> 6;
  const int l16 = lane & 15, quad = lane >> 4;
  const int wm = w >> 2, wn = w & 3;

  // T1 bijective XCD swizzle (all grids have nwg % 8 == 0)
  const int nbx = gridDim.x, nby = gridDim.y;
  const int bid = blockIdx.x + nbx * (blockIdx.y + nby * blockIdx.z);
  const int nwg = nbx * nby * (int)gridDim.z;
  int lg = (bid & 7) * (nwg >> 3) + (bid >> 3);
  const int bz = lg / (nbx * nby); lg -= bz * nbx * nby;
  const int by = lg / nbx, bx = lg - by * nbx;

  const int n0 = bx * 256;
  const int m0 = bz * MperZ + by * 256;
  const unsigned short* Be = Bw + (size_t)bz * bslab;

  if (EPI == 2) { if (tid < 256) toks[tid] = s2t[m0 + tid]; }

  // ---- staging: wave w stages chunks {w, w+8}; chunk = 16 rows x 64B = 1KiB.
  // lane l -> phys byte l*16 in chunk = row (l>>2), pos (l&3); logical k-pos =
  // pos ^ (row&3) -> per-lane global k-offset cst32.
  const int cst32 = (((lane & 3) ^ ((lane >> 2) & 3)) * 8);   // elems
  const unsigned short* aS[2];
  const unsigned short* bS[2];
  int aO[2];
#pragma unroll
  for (int j = 0; j < 2; ++j) {
    const int c = j * 8 + w;                 // chunk 0..15
    const int r = c * 16 + (lane >> 2);      // row in tile 0..255
    int arow = m0 + r;
    if (GATHER) { int t = s2t[arow]; arow = (t < 0) ? 0 : t; }
    aS[j] = A  + (size_t)arow * KDIM + cst32;
    bS[j] = Be + (size_t)(n0 + r) * KDIM + cst32;
    aO[j] = c * 512 + lane * 8;              // ushort idx within slot A region
  }

  floatx4 acc[8][4];
#pragma unroll
  for (int i = 0; i < 8; ++i)
#pragma unroll
    for (int j = 0; j < 4; ++j) acc[i][j] = (floatx4){0.f, 0.f, 0.f, 0.f};

  // read-side swizzled byte col (row stride 64B): quad*16 ^ ((row&3)<<4), row&3 == l16&3
  const int cr = (quad * 16) ^ ((l16 & 3) << 4);

#define STAGE(T) {                                                            \
    const int sb = ((T) & 3) * 16384;                                         \
    const size_t kof = (size_t)(T) * 32;                                      \
    async_copy16(aS[0] + kof, &lds[sb + aO[0]]);                              \
    async_copy16(aS[1] + kof, &lds[sb + aO[1]]);                              \
    async_copy16(bS[0] + kof, &lds[sb + 8192 + aO[0]]);                       \
    async_copy16(bS[1] + kof, &lds[sb + 8192 + aO[1]]); }

  // tile body: 2 phases of 16 MFMA; B-frags read once (hoisted across phases)
#define TILE_BODY(T, DOSTAGE, WAITCODE) {                                     \
    const int sb = ((T) & 3) * 16384;                                         \
    const char* lAb = (const char*)&lds[sb];                                  \
    const char* lBb = (const char*)&lds[sb + 8192];                           \
    bf16x8 a0[4], b0[4];                                                      \
    _Pragma("unroll") for (int mf = 0; mf < 4; ++mf)                          \
      a0[mf] = *(const bf16x8*)(lAb + (wm * 128 + mf * 16 + l16) * 64 + cr);  \
    _Pragma("unroll") for (int nf = 0; nf < 4; ++nf)                          \
      b0[nf] = *(const bf16x8*)(lBb + (wn * 64 + nf * 16 + l16) * 64 + cr);   \
    if (DOSTAGE) STAGE((T) + 3);                                              \
    __builtin_amdgcn_s_barrier();                                             \
    __builtin_amdgcn_s_setprio(1);                                            \
    _Pragma("unroll") for (int mf = 0; mf < 4; ++mf)                          \
      _Pragma("unroll") for (int nf = 0; nf < 4; ++nf)                        \
        acc[mf][nf] = __builtin_amdgcn_mfma_f32_16x16x32_bf16(                \
            a0[mf], b0[nf], acc[mf][nf], 0, 0, 0);                            \
    __builtin_amdgcn_s_setprio(0);                                            \
    __builtin_amdgcn_s_barrier();                                             \
    bf16x8 a1[4];                                                             \
    _Pragma("unroll") for (int mf = 0; mf < 4; ++mf)                          \
      a1[mf] = *(const bf16x8*)(lAb + (wm * 128 + 64 + mf * 16 + l16) * 64 + cr); \
    __builtin_amdgcn_s_barrier();                                             \
    __builtin_amdgcn_s_setprio(1);                                            \
    _Pragma("unroll") for (int mf = 0; mf < 4; ++mf)                          \
      _Pragma("unroll") for (int nf = 0; nf < 4; ++nf)                        \
        acc[4 + mf][nf] = __builtin_amdgcn_mfma_f32_16x16x32_bf16(            \
            a1[mf], b0[nf], acc[4 + mf][nf], 0, 0, 0);                        \
    __builtin_amdgcn_s_setprio(0);                                            \
    WAITCODE;                                                                 \
  }

#define WAIT8 { asm volatile("s_waitcnt vmcnt(8)" ::: "memory"); __builtin_amdgcn_s_barrier(); }
#define WAIT4 { asm volatile("s_waitcnt vmcnt(4)" ::: "memory"); __builtin_amdgcn_s_barrier(); }
#define WAIT0 { asm volatile("s_waitcnt vmcnt(0)" ::: "memory"); __builtin_amdgcn_s_barrier(); }
#define WAITN { }

  const int NT = KDIM / 32;
  __syncthreads();                 // toks visible; clean vmcnt baseline
  STAGE(0); STAGE(1); STAGE(2);    // 12 loads in flight
  asm volatile("s_waitcnt vmcnt(8)" ::: "memory");   // tile 0 landed
  __builtin_amdgcn_s_barrier();

  for (int t = 0; t < NT - 3; ++t) TILE_BODY(t, 1, WAIT8);
  TILE_BODY(NT - 3, 0, WAIT4);
  TILE_BODY(NT - 2, 0, WAIT0);
  TILE_BODY(NT - 1, 0, WAITN);

#undef TILE_BODY
#undef STAGE
#undef WAIT8
#undef WAIT4
#undef WAIT0
#undef WAITN

  // ------------------------------- epilogue ---------------------------------
  if (EPI == 0) {
    // interleaved W13: n-frag pairs (2q, 2q+1) = W1/W3 of the SAME 16 hidden
    // cols. h = n0/2 + wn*32 + q*16 + l16.
    unsigned short* Hout = (unsigned short*)OutP;
#pragma unroll
    for (int qm = 0; qm < 2; ++qm)
#pragma unroll
      for (int mf = 0; mf < 4; ++mf) {
        const int mrow = m0 + wm * 128 + qm * 64 + mf * 16 + quad * 4;
#pragma unroll
        for (int qn = 0; qn < 2; ++qn) {
          const int hcol = (n0 >> 1) + wn * 32 + qn * 16 + l16;
#pragma unroll
          for (int rr = 0; rr < 4; ++rr) {
            float v1 = acc[qm * 4 + mf][qn * 2 + 0][rr];
            float v3 = acc[qm * 4 + mf][qn * 2 + 1][rr];
            float hv = (v1 / (1.f + __expf(-v1))) * v3;
            Hout[(size_t)(mrow + rr) * HDIM + hcol] = f2bf(hv);
          }
        }
      }
  } else {
    float* Out = (float*)OutP;
#pragma unroll
    for (int qm = 0; qm < 2; ++qm)
#pragma unroll
      for (int mf = 0; mf < 4; ++mf) {
        const int mb = wm * 128 + qm * 64 + mf * 16 + quad * 4;
#pragma unroll
        for (int nf = 0; nf < 4; ++nf) {
          const int n = n0 + wn * 64 + nf * 16 + l16;
#pragma unroll
          for (int rr = 0; rr < 4; ++rr) {
            const float v = acc[qm * 4 + mf][nf][rr];
            if (EPI == 1) {
              Out[(size_t)(m0 + mb + rr) * DDIM + n] = v;
            } else {
              const int t = toks[mb + rr];
              if (t >= 0) Out[(size_t)t * DDIM + n] += gk[t] * v;
            }
          }
        }
      }
  }
}

// ---------------------------------------------------------------------------
extern "C" void kernel_launch(void* const* d_in, const int* in_sizes, int n_in,
                              void* d_out, int out_size, void* d_ws, size_t ws_size,
                              hipStream_t stream) {
  const float* x   = (const float*)d_in[0];
  const float* Wg  = (const float*)d_in[1];
  const float* W1  = (const float*)d_in[2];
  const float* W3  = (const float*)d_in[3];
  const float* W2  = (const float*)d_in[4];
  const float* sw1 = (const float*)d_in[5];
  const float* sw3 = (const float*)d_in[6];
  const float* sw2 = (const float*)d_in[7];
  float* out = (float*)d_out;

  char* ws = (char*)d_ws;
  size_t off = 0;
  auto alloc = [&](size_t bytes) -> void* {
    void* p = ws + off;
    off = (off + bytes + 255) & ~(size_t)255;
    return p;
  };
  int*   eidx     = (int*)alloc((size_t)T_TOK * 4);
  float* gate     = (float*)alloc((size_t)T_TOK * 4);
  int*   slot2tok = (int*)alloc((size_t)T_TOK * 4);
  float* gatek    = (float*)alloc((size_t)T_TOK * 4);
  unsigned short* xbf  = (unsigned short*)alloc((size_t)T_TOK * DDIM * 2);
  unsigned short* W13t = (unsigned short*)alloc((size_t)ENUM * NP13 * DDIM * 2);
  unsigned short* W2t  = (unsigned short*)alloc((size_t)ENUM * DDIM * HDIM * 2);
  unsigned short* s13t = (unsigned short*)alloc((size_t)NP13 * DDIM * 2);
  unsigned short* ssw2 = (unsigned short*)alloc((size_t)DDIM * HDIM * 2);
  unsigned short* hexp = (unsigned short*)alloc((size_t)T_TOK * HDIM * 2);
  unsigned short* hsh  = (unsigned short*)alloc((size_t)T_TOK * HDIM * 2);
  if (off > ws_size) {
    hipMemsetAsync(d_out, 0, (size_t)out_size * 4, stream);
    return;
  }

  router_cast_kernel<<<T_TOK / 4, 256, 0, stream>>>(x, Wg, eidx, gate, xbf);
  scan_kernel<<<1, 256, 0, stream>>>(eidx, gate, slot2tok, gatek);

  // weight transforms: W1/W3 -> interleaved W13 (modes 1/2); W2 plain (mode 0)
  transpose_cast_kernel<<<dim3(HDIM / 64, DDIM / 64, ENUM), 256, 0, stream>>>(
      W1, W13t, DDIM, HDIM, 1, (size_t)NP13 * DDIM);
  transpose_cast_kernel<<<dim3(HDIM / 64, DDIM / 64, ENUM), 256, 0, stream>>>(
      W3, W13t, DDIM, HDIM, 2, (size_t)NP13 * DDIM);
  transpose_cast_kernel<<<dim3(DDIM / 64, HDIM / 64, ENUM), 256, 0, stream>>>(
      W2, W2t, HDIM, DDIM, 0, (size_t)DDIM * HDIM);
  transpose_cast_kernel<<<dim3(HDIM / 64, DDIM / 64, 1), 256, 0, stream>>>(
      sw1, s13t, DDIM, HDIM, 1, 0);
  transpose_cast_kernel<<<dim3(HDIM / 64, DDIM / 64, 1), 256, 0, stream>>>(
      sw3, s13t, DDIM, HDIM, 2, 0);
  transpose_cast_kernel<<<dim3(DDIM / 64, HDIM / 64, 1), 256, 0, stream>>>(
      sw2, ssw2, HDIM, DDIM, 0, 0);

  // hidden activations: h = silu(x@W1)*(x@W3)  (EPI=0)
  gemm256<0, true,  DDIM><<<dim3(NP13 / 256, CAPS / 256, ENUM), 512, 0, stream>>>(
      xbf, slot2tok, W13t, (size_t)NP13 * DDIM, hexp, nullptr, CAPS);
  gemm256<0, false, DDIM><<<dim3(NP13 / 256, T_TOK / 256, 1), 512, 0, stream>>>(
      xbf, nullptr, s13t, 0, hsh, nullptr, T_TOK);

  // down-projections: shared writes out fully (EPI=1), expert scatter-adds (EPI=2)
  gemm256<1, false, HDIM><<<dim3(DDIM / 256, T_TOK / 256, 1), 512, 0, stream>>>(
      hsh, nullptr, ssw2, 0, out, nullptr, T_TOK);
  gemm256<2, false, HDIM><<<dim3(DDIM / 256, CAPS / 256, ENUM), 512, 0, stream>>>(
      hexp, slot2tok, W2t, (size_t)DDIM * HDIM, out, gatek, CAPS);
}